// Round 1
// baseline (143.269 us; speedup 1.0000x reference)
//
#include <hip/hip_runtime.h>
#include <math.h>

#define HH   128
#define WW   160
#define HWN  (HH*WW)      // 20480
#define NCF  32           // feature channels
#define NCD  8            // deps channels
#define ND   32           // depths
#define NV   3            // views
#define LAMBF 1.5f

// ---------------------------------------------------------------------------
// Setup: proj_v @ inv(proj_ref) for v=1,2 -> ws[0..23] = {rot(9), tr(3)} x 2
// ---------------------------------------------------------------------------
__global__ void setup_proj_k(const float* __restrict__ proj, float* __restrict__ ws) {
    if (threadIdx.x != 0 || blockIdx.x != 0) return;
    // Gauss-Jordan inverse of view-0 4x4 (with partial pivoting)
    float A[4][8];
    for (int r = 0; r < 4; r++)
        for (int c = 0; c < 4; c++) { A[r][c] = proj[r*4 + c]; A[r][c+4] = (r == c) ? 1.f : 0.f; }
    for (int col = 0; col < 4; col++) {
        int piv = col; float best = fabsf(A[col][col]);
        for (int r = col + 1; r < 4; r++) { float v = fabsf(A[r][col]); if (v > best) { best = v; piv = r; } }
        if (piv != col) for (int c = 0; c < 8; c++) { float tmp = A[col][c]; A[col][c] = A[piv][c]; A[piv][c] = tmp; }
        float inv = 1.f / A[col][col];
        for (int c = 0; c < 8; c++) A[col][c] *= inv;
        for (int r = 0; r < 4; r++) {
            if (r == col) continue;
            float f = A[r][col];
            for (int c = 0; c < 8; c++) A[r][c] -= f * A[col][c];
        }
    }
    for (int v = 1; v < NV; v++) {
        const float* S = proj + v*16;
        float P[12];
        for (int r = 0; r < 3; r++)
            for (int c = 0; c < 4; c++) {
                float acc = 0.f;
                for (int k = 0; k < 4; k++) acc += S[r*4 + k] * A[k][c + 4];
                P[r*4 + c] = acc;
            }
        float* o = ws + (v - 1)*12;
        o[0] = P[0]; o[1] = P[1]; o[2]  = P[2];
        o[3] = P[4]; o[4] = P[5]; o[5]  = P[6];
        o[6] = P[8]; o[7] = P[9]; o[8]  = P[10];
        o[9] = P[3]; o[10] = P[7]; o[11] = P[11];
    }
}

// ---------------------------------------------------------------------------
// Transpose (V,CH,H,W) -> (V,H*W,CH), channel-last, LDS-tiled
// ---------------------------------------------------------------------------
template <int CH>
__global__ __launch_bounds__(256) void transpose_k(const float* __restrict__ in,
                                                   float* __restrict__ out) {
    __shared__ float lds[CH][33];
    const int xb = blockIdx.x * 32;
    const int y  = blockIdx.y;
    const int v  = blockIdx.z;
    const float* src = in + (size_t)(v*CH)*HWN + y*WW + xb;
    #pragma unroll
    for (int i = threadIdx.x; i < CH*32; i += 256) {
        int c = i >> 5, xl = i & 31;
        lds[c][xl] = src[c*HWN + xl];
    }
    __syncthreads();
    float* dst = out + (size_t)(v*HWN + y*WW + xb) * CH;
    #pragma unroll
    for (int i = threadIdx.x; i < CH*32; i += 256) {
        int c = i % CH, xl = i / CH;
        dst[i] = lds[c][xl];   // dst[xl*CH + c]
    }
}

// ---------------------------------------------------------------------------
// Main: cost volume + softmax + depth/exp_variance
// block = 32 depths x 8 pixels; grid = HWN/8
// ---------------------------------------------------------------------------
__global__ __launch_bounds__(256) void cost_volume_k(
    const float* __restrict__ featT,   // (V,HW,32)
    const float* __restrict__ depsT,   // (V,HW,8)
    const float* __restrict__ dvals,   // (D,HW)
    const float* __restrict__ regw,    // 40
    const float* __restrict__ pws,     // 24
    float* __restrict__ out)
{
    const int t   = threadIdx.x;
    const int d   = t & 31;
    const int pix = blockIdx.x * 8 + (t >> 5);
    const int y   = pix / WW;
    const int x   = pix - y * WW;
    const float dv = dvals[d*HWN + pix];
    const float fx = (float)x, fy = (float)y;

    int   offF[2][4];
    int   offD[2][4];
    float wgt[2][4];
    #pragma unroll
    for (int v = 0; v < 2; v++) {
        const float* p = pws + v*12;
        float rx = p[0]*fx + p[1]*fy + p[2];
        float ry = p[3]*fx + p[4]*fy + p[5];
        float rz = p[6]*fx + p[7]*fy + p[8];
        float pz = rz*dv + p[11];
        float px = (rx*dv + p[9])  / pz;
        float py = (ry*dv + p[10]) / pz;
        float x0f = floorf(px), y0f = floorf(py);
        int   x0 = (int)x0f, y0 = (int)y0f;
        float wx = px - x0f, wy = py - y0f;
        float omx = 1.f - wx, omy = 1.f - wy;
        float ww[4] = { omx*omy, wx*omy, omx*wy, wx*wy };
        #pragma unroll
        for (int k = 0; k < 4; k++) {
            int xi = x0 + (k & 1), yi = y0 + (k >> 1);
            bool valid = (xi >= 0) && (xi < WW) && (yi >= 0) && (yi < HH);
            int xc = min(max(xi, 0), WW - 1);
            int yc = min(max(yi, 0), HH - 1);
            int lin = (v + 1)*HWN + yc*WW + xc;
            offF[v][k] = lin * NCF;
            offD[v][k] = lin * NCD;
            wgt[v][k]  = valid ? ww[k] : 0.f;
        }
    }

    const float inv3 = 0.3333333333333f;
    float cost = 0.f;

    const float wa0 = wgt[0][0], wa1 = wgt[0][1], wa2 = wgt[0][2], wa3 = wgt[0][3];
    const float wb0 = wgt[1][0], wb1 = wgt[1][1], wb2 = wgt[1][2], wb3 = wgt[1][3];

    // ---- 32 feature channels, 8 groups of float4 ----
    #pragma unroll
    for (int cg = 0; cg < 8; cg++) {
        float4 r  = *(const float4*)(featT + pix*NCF      + cg*4);
        float4 a0 = *(const float4*)(featT + offF[0][0] + cg*4);
        float4 a1 = *(const float4*)(featT + offF[0][1] + cg*4);
        float4 a2 = *(const float4*)(featT + offF[0][2] + cg*4);
        float4 a3 = *(const float4*)(featT + offF[0][3] + cg*4);
        float4 b0 = *(const float4*)(featT + offF[1][0] + cg*4);
        float4 b1 = *(const float4*)(featT + offF[1][1] + cg*4);
        float4 b2 = *(const float4*)(featT + offF[1][2] + cg*4);
        float4 b3 = *(const float4*)(featT + offF[1][3] + cg*4);
        float4 wv = *(const float4*)(regw + cg*4);
        const float* rp  = (const float*)&r;
        const float* wvp = (const float*)&wv;
        #pragma unroll
        for (int j = 0; j < 4; j++) {
            float s1 = ((const float*)&a0)[j]*wa0 + ((const float*)&a1)[j]*wa1
                     + ((const float*)&a2)[j]*wa2 + ((const float*)&a3)[j]*wa3;
            float s2 = ((const float*)&b0)[j]*wb0 + ((const float*)&b1)[j]*wb1
                     + ((const float*)&b2)[j]*wb2 + ((const float*)&b3)[j]*wb3;
            float rr = rp[j];
            float s  = rr + s1 + s2;
            float sq = rr*rr + s1*s1 + s2*s2;
            float sm = s * inv3;
            float var = sq * inv3 - sm * sm;
            cost += var * wvp[j];
        }
    }

    // ---- 8 deps channels, 2 groups of float4 ----
    #pragma unroll
    for (int cg = 0; cg < 2; cg++) {
        float4 r  = *(const float4*)(depsT + pix*NCD      + cg*4);
        float4 a0 = *(const float4*)(depsT + offD[0][0] + cg*4);
        float4 a1 = *(const float4*)(depsT + offD[0][1] + cg*4);
        float4 a2 = *(const float4*)(depsT + offD[0][2] + cg*4);
        float4 a3 = *(const float4*)(depsT + offD[0][3] + cg*4);
        float4 b0 = *(const float4*)(depsT + offD[1][0] + cg*4);
        float4 b1 = *(const float4*)(depsT + offD[1][1] + cg*4);
        float4 b2 = *(const float4*)(depsT + offD[1][2] + cg*4);
        float4 b3 = *(const float4*)(depsT + offD[1][3] + cg*4);
        float4 wv = *(const float4*)(regw + NCF + cg*4);
        const float* rp  = (const float*)&r;
        const float* wvp = (const float*)&wv;
        #pragma unroll
        for (int j = 0; j < 4; j++) {
            float s1 = ((const float*)&a0)[j]*wa0 + ((const float*)&a1)[j]*wa1
                     + ((const float*)&a2)[j]*wa2 + ((const float*)&a3)[j]*wa3;
            float s2 = ((const float*)&b0)[j]*wb0 + ((const float*)&b1)[j]*wb1
                     + ((const float*)&b2)[j]*wb2 + ((const float*)&b3)[j]*wb3;
            float rr = rp[j];
            float s  = rr + s1 + s2;
            float sq = rr*rr + s1*s1 + s2*s2;
            float sm = s * inv3;
            float var = sq * inv3 - sm * sm;
            cost += var * wvp[j];
        }
    }

    // ---- softmax over the 32 depth lanes + moments ----
    float m = cost;
    #pragma unroll
    for (int o = 16; o >= 1; o >>= 1) m = fmaxf(m, __shfl_xor(m, o, 32));
    float e = __expf(cost - m);
    float ssum = e;
    #pragma unroll
    for (int o = 16; o >= 1; o >>= 1) ssum += __shfl_xor(ssum, o, 32);
    float p = e / ssum;

    float pd = p * dv;
    #pragma unroll
    for (int o = 16; o >= 1; o >>= 1) pd += __shfl_xor(pd, o, 32);
    float depth = pd;

    float dd = dv - depth;
    float sv = p * dd * dd;
    #pragma unroll
    for (int o = 16; o >= 1; o >>= 1) sv += __shfl_xor(sv, o, 32);
    float ev = LAMBF * sqrtf(sv);

    out[2*HWN + d*HWN + pix] = p;          // prob_volume (D,HW)
    if (d == 0) {
        out[pix]       = depth;            // depth
        out[HWN + pix] = ev;               // exp_variance
    }
}

// ---------------------------------------------------------------------------
extern "C" void kernel_launch(void* const* d_in, const int* in_sizes, int n_in,
                              void* d_out, int out_size, void* d_ws, size_t ws_size,
                              hipStream_t stream) {
    const float* features = (const float*)d_in[0];   // (V,1,32,H,W)
    const float* deps     = (const float*)d_in[1];   // (V,1,8,H,W)
    const float* proj     = (const float*)d_in[2];   // (1,V,4,4)
    const float* dvals    = (const float*)d_in[3];   // (1,D,H,W)
    const float* regw     = (const float*)d_in[4];   // (1,40)

    float* ws    = (float*)d_ws;
    float* projw = ws;                       // 24 floats (use 64 slots)
    float* featT = ws + 64;                  // 3*HW*32 = 1,966,080 floats
    float* depsT = featT + (size_t)NV*HWN*NCF; // 3*HW*8 = 491,520 floats

    setup_proj_k<<<1, 64, 0, stream>>>(proj, projw);

    dim3 tg(WW/32, HH, NV);
    transpose_k<NCF><<<tg, 256, 0, stream>>>(features, featT);
    transpose_k<NCD><<<tg, 256, 0, stream>>>(deps, depsT);

    cost_volume_k<<<HWN/8, 256, 0, stream>>>(featT, depsT, dvals, regw, projw,
                                             (float*)d_out);
}